// Round 1
// baseline (3183.850 us; speedup 1.0000x reference)
//
#include <hip/hip_runtime.h>
#include <hip/hip_bf16.h>
#include <math.h>

#define B_    2
#define S_    2048
#define HID_  2048
#define H_    16
#define HKV_  4
#define HD_   128
#define NREP_ (H_/HKV_)
#define BS_   (B_*S_)          // 4096 rows

#define NEG_INF (-3.0e38f)

// ---------------------------------------------------------------------------
// GEMM (NT): C[M][N] = A[M][K] @ W[N][K]^T      (fp32, vector ALU)
// 128x128 tile, BK=32, 256 threads, 8x8 register microtile.
// ---------------------------------------------------------------------------
#define GBM 128
#define GBN 128
#define GBK 32
#define GPAD 4   // LDS row pad (floats), keeps 16B alignment

__global__ __launch_bounds__(256) void gemm_nt_f32(
    const float* __restrict__ A, const float* __restrict__ W,
    float* __restrict__ C, int M, int N, int K)
{
  __shared__ float As[GBK][GBM + GPAD];   // K-major (transposed on store)
  __shared__ float Ws[GBK][GBN + GPAD];

  const int bm  = blockIdx.y * GBM;
  const int bn  = blockIdx.x * GBN;
  const int tid = threadIdx.x;
  const int tx  = tid & 15;   // col group (8 cols)
  const int ty  = tid >> 4;   // row group (8 rows)

  float acc[8][8];
#pragma unroll
  for (int i = 0; i < 8; ++i)
#pragma unroll
    for (int j = 0; j < 8; ++j) acc[i][j] = 0.f;

  for (int k0 = 0; k0 < K; k0 += GBK) {
    // Stage tiles: 128 rows x 32 k = 1024 float4 per tile; 4 per thread each.
#pragma unroll
    for (int p = 0; p < 4; ++p) {
      int f   = tid + p * 256;
      int row = f >> 3;
      int kc  = (f & 7) << 2;
      float4 va = *(const float4*)(A + (size_t)(bm + row) * K + k0 + kc);
      As[kc + 0][row] = va.x; As[kc + 1][row] = va.y;
      As[kc + 2][row] = va.z; As[kc + 3][row] = va.w;
      float4 vw = *(const float4*)(W + (size_t)(bn + row) * K + k0 + kc);
      Ws[kc + 0][row] = vw.x; Ws[kc + 1][row] = vw.y;
      Ws[kc + 2][row] = vw.z; Ws[kc + 3][row] = vw.w;
    }
    __syncthreads();

#pragma unroll 8
    for (int kk = 0; kk < GBK; ++kk) {
      float4 a0 = *(const float4*)&As[kk][ty * 8];
      float4 a1 = *(const float4*)&As[kk][ty * 8 + 4];
      float4 w0 = *(const float4*)&Ws[kk][tx * 8];
      float4 w1 = *(const float4*)&Ws[kk][tx * 8 + 4];
      float ar[8] = {a0.x, a0.y, a0.z, a0.w, a1.x, a1.y, a1.z, a1.w};
      float wr[8] = {w0.x, w0.y, w0.z, w0.w, w1.x, w1.y, w1.z, w1.w};
#pragma unroll
      for (int i = 0; i < 8; ++i)
#pragma unroll
        for (int j = 0; j < 8; ++j)
          acc[i][j] = fmaf(ar[i], wr[j], acc[i][j]);
    }
    __syncthreads();
  }

#pragma unroll
  for (int i = 0; i < 8; ++i) {
    float* crow = C + (size_t)(bm + ty * 8 + i) * N + bn + tx * 8;
    *(float4*)(crow)     = make_float4(acc[i][0], acc[i][1], acc[i][2], acc[i][3]);
    *(float4*)(crow + 4) = make_float4(acc[i][4], acc[i][5], acc[i][6], acc[i][7]);
  }
}

// ---------------------------------------------------------------------------
// RoPE, in place on projection output laid out [B, S, NH, HD].
// One thread owns the (d, d+64) pair -> in-place safe.
// ---------------------------------------------------------------------------
template <int NH, int LOGNH>
__global__ __launch_bounds__(256) void rope_inplace(
    float* __restrict__ p, const float* __restrict__ cosb,
    const float* __restrict__ sinb)
{
  int idx = blockIdx.x * blockDim.x + threadIdx.x;   // B*S*NH*64 threads
  int d = idx & 63;
  int h = (idx >> 6) & (NH - 1);
  int s = (idx >> (6 + LOGNH)) & (S_ - 1);
  int b = idx >> (6 + LOGNH + 11);

  size_t off = (((size_t)b * S_ + s) * NH + h) * HD_ + d;
  float x1 = p[off];
  float x2 = p[off + 64];
  float c1 = cosb[s * HD_ + d];
  float s1 = sinb[s * HD_ + d];
  float c2 = cosb[s * HD_ + d + 64];
  float s2 = sinb[s * HD_ + d + 64];
  p[off]      = x1 * c1 - x2 * s1;   // d < 64: q*cos + (-q[d+64])*sin
  p[off + 64] = x2 * c2 + x1 * s2;   // d >=64: q*cos + q[d-64]*sin
}

// ---------------------------------------------------------------------------
// Causal flash attention, fp32. QBLK=KBLK=32, 256 threads.
// Q layout [B,S,H,HD] (row stride H*HD), K/V layout [B,S,HKV,HD] (row stride
// HKV*HD). Output [B,S,H*HD]. LDS f4 slots XOR-swizzled: slot = d4 ^ (row&31).
// ---------------------------------------------------------------------------
#define QBLK 32
#define KBLK 32

__device__ __forceinline__ float4 fma4(float s, float4 v, float4 a) {
  a.x = fmaf(s, v.x, a.x); a.y = fmaf(s, v.y, a.y);
  a.z = fmaf(s, v.z, a.z); a.w = fmaf(s, v.w, a.w);
  return a;
}

__global__ __launch_bounds__(256) void attn_fwd_f32(
    const float* __restrict__ Q, const float* __restrict__ K,
    const float* __restrict__ V, float* __restrict__ O)
{
  __shared__ float qs[QBLK * HD_];
  __shared__ float ks[KBLK * HD_];
  __shared__ float vs[KBLK * HD_];
  __shared__ float ss[QBLK * 36];     // scores, stride 36 floats (9 f4)
  __shared__ float ps[QBLK * 36];     // probabilities
  __shared__ float mrow[QBLK], lrow[QBLK], frow[QBLK];
  __shared__ float psum[QBLK][8];

  float4* qs4 = (float4*)qs;
  float4* ks4 = (float4*)ks;
  float4* vs4 = (float4*)vs;
  float4* ss4 = (float4*)ss;
  float4* ps4 = (float4*)ps;

  const int tid = threadIdx.x;
  const int qt  = blockIdx.x;
  const int bh  = blockIdx.y;
  const int b   = bh >> 4;            // / H_
  const int h   = bh & 15;
  const int kh  = h >> 2;             // / NREP_
  const int q0  = qt * QBLK;

  const float* Qbase = Q + (((size_t)b * S_ + q0) * H_ + h) * HD_;     // row stride H_*HD_
  const float* Kbase = K + ((size_t)b * S_ * HKV_ + kh) * HD_;         // row stride HKV_*HD_
  const float* Vbase = V + ((size_t)b * S_ * HKV_ + kh) * HD_;

  const float scale = 0.08838834764831845f;   // 1/sqrt(128)

  // load Q tile (pre-scaled): 32 rows x 32 f4
#pragma unroll
  for (int p = 0; p < 4; ++p) {
    int f  = tid + p * 256;
    int r  = f >> 5;
    int d4 = f & 31;
    float4 v = *(const float4*)(Qbase + (size_t)r * (H_ * HD_) + d4 * 4);
    v.x *= scale; v.y *= scale; v.z *= scale; v.w *= scale;
    qs4[r * 32 + (d4 ^ r)] = v;
  }
  if (tid < QBLK) { mrow[tid] = NEG_INF; lrow[tid] = 0.f; frow[tid] = 1.f; }

  const int txd = tid & 15;   // PV: d-slot pair {2*txd, 2*txd+1}
  const int tyr = tid >> 4;   // PV: row pair {2*tyr, 2*tyr+1}
  float4 oacc[2][2];
#pragma unroll
  for (int i = 0; i < 2; ++i)
#pragma unroll
    for (int j = 0; j < 2; ++j) oacc[i][j] = make_float4(0.f, 0.f, 0.f, 0.f);

  __syncthreads();

  const int ntiles = qt + 1;
  for (int kt = 0; kt < ntiles; ++kt) {
    // ---- stage K/V tile ----
#pragma unroll
    for (int p = 0; p < 4; ++p) {
      int f  = tid + p * 256;
      int r  = f >> 5;
      int d4 = f & 31;
      size_t g = (size_t)(kt * KBLK + r) * (HKV_ * HD_) + d4 * 4;
      ks4[r * 32 + (d4 ^ r)] = *(const float4*)(Kbase + g);
      vs4[r * 32 + (d4 ^ r)] = *(const float4*)(Vbase + g);
    }
    __syncthreads();

    // ---- Phase A: scores (2 rows x 2 cols per thread) ----
    {
      const int r0 = (tid >> 4) * 2, r1 = r0 + 1;
      const int c0 = (tid & 15) * 2, c1 = c0 + 1;
      float s00 = 0.f, s01 = 0.f, s10 = 0.f, s11 = 0.f;
#pragma unroll 8
      for (int d4 = 0; d4 < 32; ++d4) {
        float4 qa = qs4[r0 * 32 + (d4 ^ r0)];
        float4 qb = qs4[r1 * 32 + (d4 ^ r1)];
        float4 ka = ks4[c0 * 32 + (d4 ^ c0)];
        float4 kb = ks4[c1 * 32 + (d4 ^ c1)];
        s00 = fmaf(qa.x, ka.x, s00); s00 = fmaf(qa.y, ka.y, s00);
        s00 = fmaf(qa.z, ka.z, s00); s00 = fmaf(qa.w, ka.w, s00);
        s01 = fmaf(qa.x, kb.x, s01); s01 = fmaf(qa.y, kb.y, s01);
        s01 = fmaf(qa.z, kb.z, s01); s01 = fmaf(qa.w, kb.w, s01);
        s10 = fmaf(qb.x, ka.x, s10); s10 = fmaf(qb.y, ka.y, s10);
        s10 = fmaf(qb.z, ka.z, s10); s10 = fmaf(qb.w, ka.w, s10);
        s11 = fmaf(qb.x, kb.x, s11); s11 = fmaf(qb.y, kb.y, s11);
        s11 = fmaf(qb.z, kb.z, s11); s11 = fmaf(qb.w, kb.w, s11);
      }
      if (kt == qt) {   // diagonal tile: mask local c > local r
        if (c0 > r0) s00 = NEG_INF;
        if (c1 > r0) s01 = NEG_INF;
        if (c0 > r1) s10 = NEG_INF;
        if (c1 > r1) s11 = NEG_INF;
      }
      ss[r0 * 36 + c0] = s00; ss[r0 * 36 + c1] = s01;
      ss[r1 * 36 + c0] = s10; ss[r1 * 36 + c1] = s11;
    }
    __syncthreads();

    // ---- Phase B1: online softmax (8 threads per row) ----
    {
      const int r  = tid >> 3;
      const int q8 = tid & 7;
      float m_old = mrow[r];
      float mx = m_old;
#pragma unroll
      for (int c4 = 0; c4 < 8; ++c4) {
        float4 t = ss4[r * 9 + c4];
        mx = fmaxf(mx, fmaxf(fmaxf(t.x, t.y), fmaxf(t.z, t.w)));
      }
      float4 t = ss4[r * 9 + q8];
      float4 p;
      p.x = __expf(t.x - mx); p.y = __expf(t.y - mx);
      p.z = __expf(t.z - mx); p.w = __expf(t.w - mx);
      ps4[r * 9 + q8] = p;
      psum[r][q8] = p.x + p.y + p.z + p.w;
      if (q8 == 0) { frow[r] = __expf(m_old - mx); mrow[r] = mx; }
    }
    __syncthreads();

    // ---- Phase B1b: l update ----
    if (tid < QBLK) {
      float s = 0.f;
#pragma unroll
      for (int q8 = 0; q8 < 8; ++q8) s += psum[tid][q8];
      lrow[tid] = lrow[tid] * frow[tid] + s;
    }

    // ---- Phase B2: PV accumulate (2 rows x 8 d per thread) ----
    {
      const int r0 = tyr * 2, r1 = r0 + 1;
      float f0 = frow[r0], f1 = frow[r1];
      oacc[0][0].x *= f0; oacc[0][0].y *= f0; oacc[0][0].z *= f0; oacc[0][0].w *= f0;
      oacc[0][1].x *= f0; oacc[0][1].y *= f0; oacc[0][1].z *= f0; oacc[0][1].w *= f0;
      oacc[1][0].x *= f1; oacc[1][0].y *= f1; oacc[1][0].z *= f1; oacc[1][0].w *= f1;
      oacc[1][1].x *= f1; oacc[1][1].y *= f1; oacc[1][1].z *= f1; oacc[1][1].w *= f1;
#pragma unroll
      for (int c4 = 0; c4 < 8; ++c4) {
        float4 pa = ps4[r0 * 9 + c4];
        float4 pb = ps4[r1 * 9 + c4];
        const float pav[4] = {pa.x, pa.y, pa.z, pa.w};
        const float pbv[4] = {pb.x, pb.y, pb.z, pb.w};
#pragma unroll
        for (int cc = 0; cc < 4; ++cc) {
          int c = c4 * 4 + cc;
          float4 v0 = vs4[c * 32 + ((txd * 2)     ^ c)];
          float4 v1 = vs4[c * 32 + ((txd * 2 + 1) ^ c)];
          oacc[0][0] = fma4(pav[cc], v0, oacc[0][0]);
          oacc[0][1] = fma4(pav[cc], v1, oacc[0][1]);
          oacc[1][0] = fma4(pbv[cc], v0, oacc[1][0]);
          oacc[1][1] = fma4(pbv[cc], v1, oacc[1][1]);
        }
      }
    }
    __syncthreads();   // protects ss/ps/ks/vs for next tile, lrow for final
  }

  // ---- epilogue: normalize and write O [B,S,H*HD] ----
  {
    const int r0 = tyr * 2, r1 = r0 + 1;
    float inv0 = 1.f / lrow[r0];
    float inv1 = 1.f / lrow[r1];
    float* o0 = O + ((size_t)b * S_ + q0 + r0) * (H_ * HD_) + h * HD_;
    float* o1 = O + ((size_t)b * S_ + q0 + r1) * (H_ * HD_) + h * HD_;
#pragma unroll
    for (int j = 0; j < 2; ++j) {
      float4 a = oacc[0][j];
      a.x *= inv0; a.y *= inv0; a.z *= inv0; a.w *= inv0;
      *(float4*)(o0 + (txd * 2 + j) * 4) = a;
      float4 c = oacc[1][j];
      c.x *= inv1; c.y *= inv1; c.z *= inv1; c.w *= inv1;
      *(float4*)(o1 + (txd * 2 + j) * 4) = c;
    }
  }
}

// ---------------------------------------------------------------------------
extern "C" void kernel_launch(void* const* d_in, const int* in_sizes, int n_in,
                              void* d_out, int out_size, void* d_ws, size_t ws_size,
                              hipStream_t stream) {
  const float* x    = (const float*)d_in[0];
  const float* cosb = (const float*)d_in[1];
  const float* sinb = (const float*)d_in[2];
  const float* wq   = (const float*)d_in[3];
  const float* wk   = (const float*)d_in[4];
  const float* wv   = (const float*)d_in[5];
  const float* wo   = (const float*)d_in[6];
  float* out        = (float*)d_out;

  // workspace: q_proj 8M | k_proj 2M | v_proj 2M | attn 8M floats = 80 MB
  float* q_proj = (float*)d_ws;
  float* k_proj = q_proj + (size_t)BS_ * (H_ * HD_);
  float* v_proj = k_proj + (size_t)BS_ * (HKV_ * HD_);
  float* attnb  = v_proj + (size_t)BS_ * (HKV_ * HD_);

  dim3 blk(256);

  // QKV projections
  gemm_nt_f32<<<dim3((H_ * HD_) / GBN, BS_ / GBM), blk, 0, stream>>>(
      x, wq, q_proj, BS_, H_ * HD_, HID_);
  gemm_nt_f32<<<dim3((HKV_ * HD_) / GBN, BS_ / GBM), blk, 0, stream>>>(
      x, wk, k_proj, BS_, HKV_ * HD_, HID_);
  gemm_nt_f32<<<dim3((HKV_ * HD_) / GBN, BS_ / GBM), blk, 0, stream>>>(
      x, wv, v_proj, BS_, HKV_ * HD_, HID_);

  // RoPE in place on q_proj / k_proj
  rope_inplace<H_, 4><<<(B_ * S_ * H_ * 64) / 256, blk, 0, stream>>>(q_proj, cosb, sinb);
  rope_inplace<HKV_, 2><<<(B_ * S_ * HKV_ * 64) / 256, blk, 0, stream>>>(k_proj, cosb, sinb);

  // causal SDPA
  attn_fwd_f32<<<dim3(S_ / QBLK, B_ * H_), blk, 0, stream>>>(q_proj, k_proj, v_proj, attnb);

  // output projection
  gemm_nt_f32<<<dim3(HID_ / GBN, BS_ / GBM), blk, 0, stream>>>(
      attnb, wo, out, BS_, HID_, HID_);
}

// Round 2
// 490.578 us; speedup vs baseline: 6.4900x; 6.4900x over previous
//
#include <hip/hip_runtime.h>
#include <hip/hip_bf16.h>
#include <math.h>

#define B_    2
#define S_    2048
#define HID_  2048
#define H_    16
#define HKV_  4
#define HD_   128
#define BS_   (B_*S_)

typedef __attribute__((ext_vector_type(8))) short bf16x8;
typedef __attribute__((ext_vector_type(4))) float f32x4;
typedef unsigned int uint;
typedef unsigned short ushort_t;

typedef __attribute__((address_space(3))) void lds_void;
typedef __attribute__((address_space(1))) const void gbl_cvoid;

__device__ __forceinline__ void load_lds16(const void* g, void* l) {
  __builtin_amdgcn_global_load_lds((gbl_cvoid*)g, (lds_void*)l, 16, 0, 0);
}

__device__ __forceinline__ unsigned short f2bf(float f) {
  uint u = __float_as_uint(f);
  u = (u + 0x7fff + ((u >> 16) & 1)) >> 16;   // RNE
  return (unsigned short)u;
}
__device__ __forceinline__ float bf2f(unsigned short u) {
  return __uint_as_float(((uint)u) << 16);
}

// ---------------------------------------------------------------------------
// fp32 -> bf16 cast
// ---------------------------------------------------------------------------
__global__ __launch_bounds__(256) void cast_f32_bf16(
    const float* __restrict__ src, unsigned short* __restrict__ dst, int n)
{
  int i = (blockIdx.x * 256 + threadIdx.x) * 4;
  if (i < n) {
    float4 v = *(const float4*)(src + i);
    ushort4 o;
    o.x = f2bf(v.x); o.y = f2bf(v.y); o.z = f2bf(v.z); o.w = f2bf(v.w);
    *(ushort4*)(dst + i) = o;
  }
}

// ---------------------------------------------------------------------------
// bf16 NT-GEMM (m97 structure): C[M][N] = A[M][K] @ W[N][K]^T, fp32 accum.
// 128x128 tile, BK=32, 256 threads (4 waves, 2x2 of 64x64), MFMA 16x16x32.
// LDS rows 64B, XOR-swizzle ((row&3)<<4) applied on BOTH global-src (staging)
// and ds_read side (rule #21) -> conflict-free ds_read_b128.
// ---------------------------------------------------------------------------
template <int WRITE_BF16>
__global__ __launch_bounds__(256) void gemm_nt_bf16(
    const unsigned short* __restrict__ A, const unsigned short* __restrict__ W,
    void* __restrict__ Cv, int M, int N, int K)
{
  __shared__ unsigned short As[128 * 32];
  __shared__ unsigned short Bs[128 * 32];

  const int tid = threadIdx.x;
  const int bm = blockIdx.y * 128, bn = blockIdx.x * 128;
  const int w = tid >> 6, lane = tid & 63;
  const int c_ = lane & 15, g4 = lane >> 4;
  const int wr = (w >> 1) * 64, wc = (w & 1) * 64;

  f32x4 acc[4][4];
#pragma unroll
  for (int i = 0; i < 4; ++i)
#pragma unroll
    for (int j = 0; j < 4; ++j) acc[i][j] = (f32x4){0.f, 0.f, 0.f, 0.f};

  for (int k0 = 0; k0 < K; k0 += 32) {
#pragma unroll
    for (int i = 0; i < 2; ++i) {
      int db = i * 4096 + tid * 16;
      int row = db >> 6;
      int cb = (db & 63) ^ ((row & 3) << 4);
      load_lds16((const char*)(A + (size_t)(bm + row) * K + k0) + cb, (char*)As + db);
      load_lds16((const char*)(W + (size_t)(bn + row) * K + k0) + cb, (char*)Bs + db);
    }
    __syncthreads();

    bf16x8 af[4], bfr[4];
#pragma unroll
    for (int i = 0; i < 4; ++i) {
      int ra = wr + i * 16 + c_;
      af[i] = *(const bf16x8*)((const char*)As + ra * 64 + ((g4 * 16) ^ ((ra & 3) << 4)));
      int rb = wc + i * 16 + c_;
      bfr[i] = *(const bf16x8*)((const char*)Bs + rb * 64 + ((g4 * 16) ^ ((rb & 3) << 4)));
    }
#pragma unroll
    for (int mi = 0; mi < 4; ++mi)
#pragma unroll
      for (int ni = 0; ni < 4; ++ni)
        acc[mi][ni] = __builtin_amdgcn_mfma_f32_16x16x32_bf16(af[mi], bfr[ni], acc[mi][ni], 0, 0, 0);
    __syncthreads();
  }

  // epilogue: C row = (lane>>4)*4 + r, col = lane&15 (m89-verified layout)
#pragma unroll
  for (int mi = 0; mi < 4; ++mi) {
#pragma unroll
    for (int r = 0; r < 4; ++r) {
      size_t row = bm + wr + mi * 16 + g4 * 4 + r;
#pragma unroll
      for (int ni = 0; ni < 4; ++ni) {
        size_t col = bn + wc + ni * 16 + c_;
        float v = acc[mi][ni][r];
        if (WRITE_BF16)
          ((unsigned short*)Cv)[row * N + col] = f2bf(v);
        else
          ((float*)Cv)[row * N + col] = v;
      }
    }
  }
}

// ---------------------------------------------------------------------------
// RoPE in place on bf16, layout rows of ROWE elems, head cols h*HD+d.
// One thread owns the (d, d+64) pair. SCALE folds 1/sqrt(HD) (for Q).
// ---------------------------------------------------------------------------
template <int NH, int LOGNH, int ROWE, int SCALE>
__global__ __launch_bounds__(256) void rope_bf16(
    unsigned short* __restrict__ p, const float* __restrict__ cosb,
    const float* __restrict__ sinb)
{
  int idx = blockIdx.x * 256 + threadIdx.x;
  int d = idx & 63;
  int h = (idx >> 6) & (NH - 1);
  int s = (idx >> (6 + LOGNH)) & (S_ - 1);
  int b = idx >> (6 + LOGNH + 11);

  size_t off = ((size_t)b * S_ + s) * ROWE + h * HD_ + d;
  float x1 = bf2f(p[off]);
  float x2 = bf2f(p[off + 64]);
  float c1 = cosb[s * HD_ + d],      s1 = sinb[s * HD_ + d];
  float c2 = cosb[s * HD_ + d + 64], s2 = sinb[s * HD_ + d + 64];
  float o1 = x1 * c1 - x2 * s1;
  float o2 = x2 * c2 + x1 * s2;
  if (SCALE) { o1 *= 0.08838834764831845f; o2 *= 0.08838834764831845f; }
  p[off]      = f2bf(o1);
  p[off + 64] = f2bf(o2);
}

// ---------------------------------------------------------------------------
// Causal flash attention, bf16 MFMA. Block = 4 waves x 16 Q-rows (QBLK=64),
// KVBLK=64. K staged via global_load_lds with ((row&7)<<4) XOR swizzle
// (pre-swizzled global src). V transposed into LDS [128][72] with kv-XOR
// ((d>>4)<<3). Online softmax per C-layout row via 16-lane shfl_xor.
// Q pre-scaled by 1/sqrt(d) in rope. KV row stride = 1024 elems (fused KV).
// ---------------------------------------------------------------------------
#define KVROW 1024   // elems per (b,s) row of fused KV buffer

__global__ __launch_bounds__(256) void attn_fwd_bf16(
    const unsigned short* __restrict__ Q, const unsigned short* __restrict__ KV,
    unsigned short* __restrict__ O)
{
  __shared__ unsigned short ks_[64 * 128];    // swizzled, 256B rows
  __shared__ unsigned short vt_[128 * 72];    // V^T [d][72], kv-swizzled
  __shared__ unsigned short pl_[4 * 16 * 72]; // per-wave P [16][72]

  const int tid = threadIdx.x;
  const int lane = tid & 63;
  const int w = tid >> 6;
  const int c_ = lane & 15, g4 = lane >> 4;

  const int qt = blockIdx.x;
  const int bh = blockIdx.y;
  const int b = bh >> 4, h = bh & 15, kh = h >> 2;
  const int q0 = qt * 64;

  // Q A-frags in registers: lane holds Q[q=c_][k = s*32 + g4*8 + j]
  bf16x8 qf[4];
  const unsigned short* qsrc =
      Q + (((size_t)b * S_ + q0 + w * 16 + c_) * H_ + h) * HD_ + g4 * 8;
#pragma unroll
  for (int s = 0; s < 4; ++s) qf[s] = *(const bf16x8*)(qsrc + s * 32);

  f32x4 o[8];
#pragma unroll
  for (int dt = 0; dt < 8; ++dt) o[dt] = (f32x4){0.f, 0.f, 0.f, 0.f};
  float m_[4], l_[4];
#pragma unroll
  for (int r = 0; r < 4; ++r) { m_[r] = -3.0e38f; l_[r] = 0.f; }

  const char* Kg = (const char*)(KV + (size_t)b * S_ * KVROW + kh * HD_);
  const unsigned short* Vg = KV + (size_t)b * S_ * KVROW + 512 + kh * HD_;
  unsigned short* pl = pl_ + w * (16 * 72);

  for (int kt = 0; kt <= qt; ++kt) {
    // ---- stage K: 64 rows x 256B, pre-swizzled source ----
#pragma unroll
    for (int p = 0; p < 4; ++p) {
      int db = p * 4096 + tid * 16;
      int row = db >> 8;
      int cb = (db & 255) ^ ((row & 7) << 4);
      load_lds16(Kg + (size_t)(kt * 64 + row) * (KVROW * 2) + cb, (char*)ks_ + db);
    }
    // ---- stage V^T: reg transpose, 2 kv-rows x 16 d per thread ----
    {
      const int kv0 = (tid >> 3) * 2;
      const int dch = tid & 7;
      const unsigned short* vs = Vg + (size_t)(kt * 64 + kv0) * KVROW + dch * 16;
      bf16x8 r0a = *(const bf16x8*)(vs);
      bf16x8 r0b = *(const bf16x8*)(vs + 8);
      bf16x8 r1a = *(const bf16x8*)(vs + KVROW);
      bf16x8 r1b = *(const bf16x8*)(vs + KVROW + 8);
      int kvs = kv0 ^ (dch << 3);
#pragma unroll
      for (int j = 0; j < 8; ++j) {
        uint w0 = (uint)(unsigned short)r0a[j] | ((uint)(unsigned short)r1a[j] << 16);
        *(uint*)&vt_[(dch * 16 + j) * 72 + kvs] = w0;
        uint w1 = (uint)(unsigned short)r0b[j] | ((uint)(unsigned short)r1b[j] << 16);
        *(uint*)&vt_[(dch * 16 + 8 + j) * 72 + kvs] = w1;
      }
    }
    __syncthreads();

    // ---- QK^T: 4 col-tiles x 4 d-steps ----
    f32x4 sc[4];
#pragma unroll
    for (int nt = 0; nt < 4; ++nt) {
      sc[nt] = (f32x4){0.f, 0.f, 0.f, 0.f};
      int row = nt * 16 + c_;
      const char* kr = (const char*)ks_ + row * 256;
      int sw = (row & 7) << 4;
#pragma unroll
      for (int ds = 0; ds < 4; ++ds) {
        bf16x8 kf = *(const bf16x8*)(kr + ((ds * 64 + g4 * 16) ^ sw));
        sc[nt] = __builtin_amdgcn_mfma_f32_16x16x32_bf16(qf[ds], kf, sc[nt], 0, 0, 0);
      }
    }

    // ---- causal mask on diagonal tile ----
    if (kt == qt) {
#pragma unroll
      for (int nt = 0; nt < 4; ++nt) {
        int kvi = nt * 16 + c_;
#pragma unroll
        for (int r = 0; r < 4; ++r) {
          int qi = w * 16 + g4 * 4 + r;
          if (kvi > qi) sc[nt][r] = -3.0e38f;
        }
      }
    }

    // ---- online softmax (row = g4*4+r, reduce across c_ via shfl) ----
    float fr_[4];
#pragma unroll
    for (int r = 0; r < 4; ++r) {
      float mx = fmaxf(fmaxf(sc[0][r], sc[1][r]), fmaxf(sc[2][r], sc[3][r]));
#pragma unroll
      for (int d = 1; d < 16; d <<= 1) mx = fmaxf(mx, __shfl_xor(mx, d, 16));
      float mn = fmaxf(m_[r], mx);
      fr_[r] = exp2f((m_[r] - mn) * 1.4426950408889634f);
      m_[r] = mn;
      float sum = 0.f;
#pragma unroll
      for (int nt = 0; nt < 4; ++nt) {
        float pv = exp2f((sc[nt][r] - mn) * 1.4426950408889634f);
        sc[nt][r] = pv;
        sum += pv;
      }
#pragma unroll
      for (int d = 1; d < 16; d <<= 1) sum += __shfl_xor(sum, d, 16);
      l_[r] = l_[r] * fr_[r] + sum;
    }
#pragma unroll
    for (int dt = 0; dt < 8; ++dt)
#pragma unroll
      for (int r = 0; r < 4; ++r) o[dt][r] *= fr_[r];

    // ---- P -> wave-private LDS (bf16) ----
#pragma unroll
    for (int nt = 0; nt < 4; ++nt)
#pragma unroll
      for (int r = 0; r < 4; ++r)
        pl[(g4 * 4 + r) * 72 + nt * 16 + c_] = f2bf(sc[nt][r]);

    // ---- PV: 8 d-tiles x 2 kv-steps ----
#pragma unroll
    for (int ksI = 0; ksI < 2; ++ksI) {
      bf16x8 pa = *(const bf16x8*)&pl[c_ * 72 + ksI * 32 + g4 * 8];
#pragma unroll
      for (int dt = 0; dt < 8; ++dt) {
        bf16x8 vf = *(const bf16x8*)&vt_[(dt * 16 + c_) * 72 +
                                         ((ksI * 32 + g4 * 8) ^ (dt << 3))];
        o[dt] = __builtin_amdgcn_mfma_f32_16x16x32_bf16(pa, vf, o[dt], 0, 0, 0);
      }
    }
    __syncthreads();
  }

  // ---- epilogue: O[b, q, h*128 + d] bf16 ----
  float inv[4];
#pragma unroll
  for (int r = 0; r < 4; ++r) inv[r] = 1.f / l_[r];
  unsigned short* ob =
      O + ((size_t)b * S_ + q0 + w * 16 + g4 * 4) * (H_ * HD_) + h * HD_ + c_;
#pragma unroll
  for (int r = 0; r < 4; ++r)
#pragma unroll
    for (int dt = 0; dt < 8; ++dt)
      ob[(size_t)r * (H_ * HD_) + dt * 16] = f2bf(o[dt][r] * inv[r]);
}

// ---------------------------------------------------------------------------
extern "C" void kernel_launch(void* const* d_in, const int* in_sizes, int n_in,
                              void* d_out, int out_size, void* d_ws, size_t ws_size,
                              hipStream_t stream) {
  const float* x    = (const float*)d_in[0];
  const float* cosb = (const float*)d_in[1];
  const float* sinb = (const float*)d_in[2];
  const float* wq   = (const float*)d_in[3];
  const float* wk   = (const float*)d_in[4];
  const float* wv   = (const float*)d_in[5];
  const float* wo   = (const float*)d_in[6];
  float* out        = (float*)d_out;

  // bf16 workspace (elem counts); total 76 MiB
  unsigned short* xb      = (unsigned short*)d_ws;
  unsigned short* wqb     = xb + 8388608;        // x:      4096x2048
  unsigned short* wkvb    = wqb + 4194304;       // wq:     2048x2048
  unsigned short* wob     = wkvb + 2097152;      // wk|wv: 1024x2048
  unsigned short* q_proj  = wob + 4194304;       // wo:     2048x2048
  unsigned short* kv_proj = q_proj + 8388608;    // q:      4096x2048
  unsigned short* attnb   = kv_proj + 4194304;   // kv:     4096x1024

  dim3 blk(256);

  // casts
  cast_f32_bf16<<<8192, blk, 0, stream>>>(x, xb, 8388608);
  cast_f32_bf16<<<4096, blk, 0, stream>>>(wq, wqb, 4194304);
  cast_f32_bf16<<<1024, blk, 0, stream>>>(wk, wkvb, 1048576);
  cast_f32_bf16<<<1024, blk, 0, stream>>>(wv, wkvb + 1048576, 1048576);
  cast_f32_bf16<<<4096, blk, 0, stream>>>(wo, wob, 4194304);

  // projections (bf16 out)
  gemm_nt_bf16<1><<<dim3(16, 32), blk, 0, stream>>>(xb, wqb, q_proj, BS_, 2048, HID_);
  gemm_nt_bf16<1><<<dim3(8, 32), blk, 0, stream>>>(xb, wkvb, kv_proj, BS_, 1024, HID_);

  // RoPE (Q gets 1/sqrt(d) folded in)
  rope_bf16<16, 4, 2048, 1><<<16384, blk, 0, stream>>>(q_proj, cosb, sinb);
  rope_bf16<4, 2, 1024, 0><<<4096, blk, 0, stream>>>(kv_proj, cosb, sinb);

  // causal SDPA
  attn_fwd_bf16<<<dim3(32, 32), blk, 0, stream>>>(q_proj, kv_proj, attnb);

  // output projection (fp32 out)
  gemm_nt_bf16<0><<<dim3(16, 32), blk, 0, stream>>>(attnb, wob, out, BS_, HID_, HID_);
}

// Round 3
// 451.384 us; speedup vs baseline: 7.0535x; 1.0868x over previous
//
#include <hip/hip_runtime.h>
#include <hip/hip_bf16.h>
#include <math.h>

#define B_    2
#define S_    2048
#define HID_  2048
#define H_    16
#define HKV_  4
#define HD_   128
#define BS_   (B_*S_)
#define QSTRIDE 3072          // fused qkv row: [q 2048 | k 512 | v 512]
#define L2E 1.4426950408889634f

typedef __attribute__((ext_vector_type(8))) short bf16x8;
typedef __attribute__((ext_vector_type(4))) float f32x4;
typedef unsigned int uint;

typedef __attribute__((address_space(3))) void lds_void;
typedef __attribute__((address_space(1))) const void gbl_cvoid;

__device__ __forceinline__ void load_lds16(const void* g, void* l) {
  __builtin_amdgcn_global_load_lds((gbl_cvoid*)g, (lds_void*)l, 16, 0, 0);
}

__device__ __forceinline__ unsigned short f2bf(float f) {
  uint u = __float_as_uint(f);
  u = (u + 0x7fff + ((u >> 16) & 1)) >> 16;   // RNE
  return (unsigned short)u;
}
__device__ __forceinline__ float bf2f(unsigned short u) {
  return __uint_as_float(((uint)u) << 16);
}

// ---------------------------------------------------------------------------
// fp32 -> bf16 cast
// ---------------------------------------------------------------------------
__global__ __launch_bounds__(256) void cast_f32_bf16(
    const float* __restrict__ src, unsigned short* __restrict__ dst, int n)
{
  int i = (blockIdx.x * 256 + threadIdx.x) * 4;
  if (i < n) {
    float4 v = *(const float4*)(src + i);
    ushort4 o;
    o.x = f2bf(v.x); o.y = f2bf(v.y); o.z = f2bf(v.z); o.w = f2bf(v.w);
    *(ushort4*)(dst + i) = o;
  }
}

// ---------------------------------------------------------------------------
// bf16 NT-GEMM (m97 structure): C[M][N] = A[M][K] @ W[N][K]^T, fp32 accum.
// 128x128 tile, BK=32, 256 threads (4 waves, 2x2 of 64x64), MFMA 16x16x32.
// ---------------------------------------------------------------------------
template <int WRITE_BF16>
__global__ __launch_bounds__(256) void gemm_nt_bf16(
    const unsigned short* __restrict__ A, const unsigned short* __restrict__ W,
    void* __restrict__ Cv, int M, int N, int K)
{
  __shared__ unsigned short As[128 * 32];
  __shared__ unsigned short Bs[128 * 32];

  const int tid = threadIdx.x;
  const int bm = blockIdx.y * 128, bn = blockIdx.x * 128;
  const int w = tid >> 6, lane = tid & 63;
  const int c_ = lane & 15, g4 = lane >> 4;
  const int wr = (w >> 1) * 64, wc = (w & 1) * 64;

  f32x4 acc[4][4];
#pragma unroll
  for (int i = 0; i < 4; ++i)
#pragma unroll
    for (int j = 0; j < 4; ++j) acc[i][j] = (f32x4){0.f, 0.f, 0.f, 0.f};

  for (int k0 = 0; k0 < K; k0 += 32) {
#pragma unroll
    for (int i = 0; i < 2; ++i) {
      int db = i * 4096 + tid * 16;
      int row = db >> 6;
      int cb = (db & 63) ^ ((row & 3) << 4);
      load_lds16((const char*)(A + (size_t)(bm + row) * K + k0) + cb, (char*)As + db);
      load_lds16((const char*)(W + (size_t)(bn + row) * K + k0) + cb, (char*)Bs + db);
    }
    __syncthreads();

    bf16x8 af[4], bfr[4];
#pragma unroll
    for (int i = 0; i < 4; ++i) {
      int ra = wr + i * 16 + c_;
      af[i] = *(const bf16x8*)((const char*)As + ra * 64 + ((g4 * 16) ^ ((ra & 3) << 4)));
      int rb = wc + i * 16 + c_;
      bfr[i] = *(const bf16x8*)((const char*)Bs + rb * 64 + ((g4 * 16) ^ ((rb & 3) << 4)));
    }
#pragma unroll
    for (int mi = 0; mi < 4; ++mi)
#pragma unroll
      for (int ni = 0; ni < 4; ++ni)
        acc[mi][ni] = __builtin_amdgcn_mfma_f32_16x16x32_bf16(af[mi], bfr[ni], acc[mi][ni], 0, 0, 0);
    __syncthreads();
  }

#pragma unroll
  for (int mi = 0; mi < 4; ++mi) {
#pragma unroll
    for (int r = 0; r < 4; ++r) {
      size_t row = bm + wr + mi * 16 + g4 * 4 + r;
#pragma unroll
      for (int ni = 0; ni < 4; ++ni) {
        size_t col = bn + wc + ni * 16 + c_;
        float v = acc[mi][ni][r];
        if (WRITE_BF16)
          ((unsigned short*)Cv)[row * N + col] = f2bf(v);
        else
          ((float*)Cv)[row * N + col] = v;
      }
    }
  }
}

// ---------------------------------------------------------------------------
// RoPE in place on bf16. Rows of ROWE elems; head cols h*HD+d (pointer pre-
// offset selects Q or K slice). One thread owns the (d, d+64) pair.
// ---------------------------------------------------------------------------
template <int NH, int LOGNH, int ROWE, int SCALE>
__global__ __launch_bounds__(256) void rope_bf16(
    unsigned short* __restrict__ p, const float* __restrict__ cosb,
    const float* __restrict__ sinb)
{
  int idx = blockIdx.x * 256 + threadIdx.x;
  int d = idx & 63;
  int h = (idx >> 6) & (NH - 1);
  int s = (idx >> (6 + LOGNH)) & (S_ - 1);
  int b = idx >> (6 + LOGNH + 11);

  size_t off = ((size_t)b * S_ + s) * ROWE + h * HD_ + d;
  float x1 = bf2f(p[off]);
  float x2 = bf2f(p[off + 64]);
  float c1 = cosb[s * HD_ + d],      s1 = sinb[s * HD_ + d];
  float c2 = cosb[s * HD_ + d + 64], s2 = sinb[s * HD_ + d + 64];
  float o1 = x1 * c1 - x2 * s1;
  float o2 = x2 * c2 + x1 * s2;
  if (SCALE) { o1 *= 0.08838834764831845f; o2 *= 0.08838834764831845f; }
  p[off]      = f2bf(o1);
  p[off + 64] = f2bf(o2);
}

// ---------------------------------------------------------------------------
// Causal flash attention, bf16 MFMA. 4 waves x 16 Q-rows (QBLK=64), KVBLK=64.
// Double-buffered K (global_load_lds, pre-swizzled src) and V (reg-staged,
// issue-early / ds_write-late). One barrier per tile. LPT block order.
// Defer-max online softmax (THR=8). Q pre-scaled by 1/sqrt(d) in rope.
// ---------------------------------------------------------------------------
__global__ __launch_bounds__(256) void attn_fwd_bf16(
    const unsigned short* __restrict__ QKV, unsigned short* __restrict__ O)
{
  __shared__ unsigned short ks_[2][64 * 128];   // swizzled, 256B rows
  __shared__ unsigned short vt_[2][128 * 72];   // V^T [d][72], kv-swizzled
  __shared__ unsigned short pl_[4][16 * 72];    // per-wave P

  const int tid = threadIdx.x;
  const int lane = tid & 63;
  const int w = tid >> 6;
  const int c_ = lane & 15, g4 = lane >> 4;

  const int qt = 31 - blockIdx.x;   // LPT: longest causal blocks first
  const int bh = blockIdx.y;
  const int b = bh >> 4, h = bh & 15, kh = h >> 2;
  const int q0 = qt * 64;

  // Q A-frags: lane holds Q[q = c_][k = s*32 + g4*8 + j]
  bf16x8 qf[4];
  const unsigned short* qsrc =
      QKV + ((size_t)b * S_ + q0 + w * 16 + c_) * QSTRIDE + h * HD_ + g4 * 8;
#pragma unroll
  for (int s = 0; s < 4; ++s) qf[s] = *(const bf16x8*)(qsrc + s * 32);

  f32x4 o[8];
#pragma unroll
  for (int dt = 0; dt < 8; ++dt) o[dt] = (f32x4){0.f, 0.f, 0.f, 0.f};
  float m_[4], l_[4];
#pragma unroll
  for (int r = 0; r < 4; ++r) { m_[r] = -3.0e38f; l_[r] = 0.f; }

  const char* Kg = (const char*)(QKV + (size_t)b * S_ * QSTRIDE + 2048 + kh * HD_);
  const unsigned short* Vg = QKV + (size_t)b * S_ * QSTRIDE + 2560 + kh * HD_;
  unsigned short* pl = pl_[w];

  const int kv0 = (tid >> 3) * 2;   // V staging: 2 kv-rows x 16 d per thread
  const int dch = tid & 7;
  const int kvs = kv0 ^ (dch << 3);
  bf16x8 vr[4];

  // ---- prologue: stage tile 0 ----
#pragma unroll
  for (int p = 0; p < 4; ++p) {
    int db = p * 4096 + tid * 16;
    int row = db >> 8;
    int cb = (db & 255) ^ ((row & 7) << 4);
    load_lds16(Kg + (size_t)row * (QSTRIDE * 2) + cb, (char*)ks_[0] + db);
  }
  {
    const unsigned short* vs = Vg + (size_t)kv0 * QSTRIDE + dch * 16;
    vr[0] = *(const bf16x8*)(vs);
    vr[1] = *(const bf16x8*)(vs + 8);
    vr[2] = *(const bf16x8*)(vs + QSTRIDE);
    vr[3] = *(const bf16x8*)(vs + QSTRIDE + 8);
  }
#pragma unroll
  for (int j = 0; j < 8; ++j) {
    uint w0 = (uint)(unsigned short)vr[0][j] | ((uint)(unsigned short)vr[2][j] << 16);
    *(uint*)&vt_[0][(dch * 16 + j) * 72 + kvs] = w0;
    uint w1 = (uint)(unsigned short)vr[1][j] | ((uint)(unsigned short)vr[3][j] << 16);
    *(uint*)&vt_[0][(dch * 16 + 8 + j) * 72 + kvs] = w1;
  }
  __syncthreads();

  for (int kt = 0; kt <= qt; ++kt) {
    const int cur = kt & 1;

    // ---- prefetch next tile: K -> LDS (async), V -> regs ----
    if (kt < qt) {
#pragma unroll
      for (int p = 0; p < 4; ++p) {
        int db = p * 4096 + tid * 16;
        int row = db >> 8;
        int cb = (db & 255) ^ ((row & 7) << 4);
        load_lds16(Kg + (size_t)((kt + 1) * 64 + row) * (QSTRIDE * 2) + cb,
                   (char*)ks_[cur ^ 1] + db);
      }
      const unsigned short* vs = Vg + (size_t)((kt + 1) * 64 + kv0) * QSTRIDE + dch * 16;
      vr[0] = *(const bf16x8*)(vs);
      vr[1] = *(const bf16x8*)(vs + 8);
      vr[2] = *(const bf16x8*)(vs + QSTRIDE);
      vr[3] = *(const bf16x8*)(vs + QSTRIDE + 8);
    }

    // ---- QK^T: 4 col-tiles x 4 d-steps ----
    f32x4 sc[4];
#pragma unroll
    for (int nt = 0; nt < 4; ++nt) {
      sc[nt] = (f32x4){0.f, 0.f, 0.f, 0.f};
      int row = nt * 16 + c_;
      const char* kr = (const char*)ks_[cur] + row * 256;
      int sw = (row & 7) << 4;
#pragma unroll
      for (int ds = 0; ds < 4; ++ds) {
        bf16x8 kf = *(const bf16x8*)(kr + ((ds * 64 + g4 * 16) ^ sw));
        sc[nt] = __builtin_amdgcn_mfma_f32_16x16x32_bf16(qf[ds], kf, sc[nt], 0, 0, 0);
      }
    }

    // ---- causal mask on diagonal tile ----
    if (kt == qt) {
#pragma unroll
      for (int nt = 0; nt < 4; ++nt) {
        int kvi = nt * 16 + c_;
#pragma unroll
        for (int r = 0; r < 4; ++r) {
          int qi = w * 16 + g4 * 4 + r;
          if (kvi > qi) sc[nt][r] = -3.0e38f;
        }
      }
    }

    // ---- online softmax with defer-max (THR=8) ----
    float mx[4];
#pragma unroll
    for (int r = 0; r < 4; ++r) {
      float m0 = fmaxf(fmaxf(sc[0][r], sc[1][r]), fmaxf(sc[2][r], sc[3][r]));
#pragma unroll
      for (int d = 1; d < 16; d <<= 1) m0 = fmaxf(m0, __shfl_xor(m0, d, 16));
      mx[r] = m0;
    }
    int needi = 0;
#pragma unroll
    for (int r = 0; r < 4; ++r) needi |= (mx[r] > m_[r] + 8.f) ? 1 : 0;
    const bool need = __any(needi);
    float fr_[4];
    if (need) {
#pragma unroll
      for (int r = 0; r < 4; ++r) {
        float mn = fmaxf(m_[r], mx[r]);
        fr_[r] = exp2f((m_[r] - mn) * L2E);
        m_[r] = mn;
      }
    } else {
#pragma unroll
      for (int r = 0; r < 4; ++r) fr_[r] = 1.f;
    }
#pragma unroll
    for (int r = 0; r < 4; ++r) {
      float sum = 0.f;
#pragma unroll
      for (int nt = 0; nt < 4; ++nt) {
        float pv = exp2f((sc[nt][r] - m_[r]) * L2E);
        sc[nt][r] = pv;
        sum += pv;
      }
#pragma unroll
      for (int d = 1; d < 16; d <<= 1) sum += __shfl_xor(sum, d, 16);
      l_[r] = l_[r] * fr_[r] + sum;
    }
    if (need) {
#pragma unroll
      for (int dt = 0; dt < 8; ++dt)
#pragma unroll
        for (int r = 0; r < 4; ++r) o[dt][r] *= fr_[r];
    }

    // ---- P -> wave-private LDS (bf16) ----
#pragma unroll
    for (int nt = 0; nt < 4; ++nt)
#pragma unroll
      for (int r = 0; r < 4; ++r)
        pl[(g4 * 4 + r) * 72 + nt * 16 + c_] = f2bf(sc[nt][r]);

    // ---- PV: 8 d-tiles x 2 kv-steps ----
#pragma unroll
    for (int ksI = 0; ksI < 2; ++ksI) {
      bf16x8 pa = *(const bf16x8*)&pl[c_ * 72 + ksI * 32 + g4 * 8];
#pragma unroll
      for (int dt = 0; dt < 8; ++dt) {
        bf16x8 vf = *(const bf16x8*)&vt_[cur][(dt * 16 + c_) * 72 +
                                             ((ksI * 32 + g4 * 8) ^ (dt << 3))];
        o[dt] = __builtin_amdgcn_mfma_f32_16x16x32_bf16(pa, vf, o[dt], 0, 0, 0);
      }
    }

    // ---- write prefetched V into next buffer (loads had whole compute to land)
    if (kt < qt) {
#pragma unroll
      for (int j = 0; j < 8; ++j) {
        uint w0 = (uint)(unsigned short)vr[0][j] | ((uint)(unsigned short)vr[2][j] << 16);
        *(uint*)&vt_[cur ^ 1][(dch * 16 + j) * 72 + kvs] = w0;
        uint w1 = (uint)(unsigned short)vr[1][j] | ((uint)(unsigned short)vr[3][j] << 16);
        *(uint*)&vt_[cur ^ 1][(dch * 16 + 8 + j) * 72 + kvs] = w1;
      }
    }
    __syncthreads();
  }

  // ---- epilogue ----
  float inv[4];
#pragma unroll
  for (int r = 0; r < 4; ++r) inv[r] = 1.f / l_[r];
  unsigned short* ob =
      O + ((size_t)b * S_ + q0 + w * 16 + g4 * 4) * (H_ * HD_) + h * HD_ + c_;
#pragma unroll
  for (int r = 0; r < 4; ++r)
#pragma unroll
    for (int dt = 0; dt < 8; ++dt)
      ob[(size_t)r * (H_ * HD_) + dt * 16] = f2bf(o[dt][r] * inv[r]);
}

// ---------------------------------------------------------------------------
extern "C" void kernel_launch(void* const* d_in, const int* in_sizes, int n_in,
                              void* d_out, int out_size, void* d_ws, size_t ws_size,
                              hipStream_t stream) {
  const float* x    = (const float*)d_in[0];
  const float* cosb = (const float*)d_in[1];
  const float* sinb = (const float*)d_in[2];
  const float* wq   = (const float*)d_in[3];
  const float* wk   = (const float*)d_in[4];
  const float* wv   = (const float*)d_in[5];
  const float* wo   = (const float*)d_in[6];
  float* out        = (float*)d_out;

  // bf16 workspace (elem offsets); total ~79.7 MB
  unsigned short* xb     = (unsigned short*)d_ws;
  unsigned short* wqkvb  = xb + 8388608;         // x:    4096x2048
  unsigned short* wob    = wqkvb + 6291456;      // wqkv: 3072x2048
  unsigned short* qkv    = wob + 4194304;        // wo:   2048x2048
  unsigned short* attnb  = qkv + 12582912;       // qkv:  4096x3072
                                                 // attn: 4096x2048

  dim3 blk(256);

  // casts (wq|wk|wv concatenated into one [3072][2048] weight)
  cast_f32_bf16<<<8192, blk, 0, stream>>>(x, xb, 8388608);
  cast_f32_bf16<<<4096, blk, 0, stream>>>(wq, wqkvb, 4194304);
  cast_f32_bf16<<<1024, blk, 0, stream>>>(wk, wqkvb + 4194304, 1048576);
  cast_f32_bf16<<<1024, blk, 0, stream>>>(wv, wqkvb + 5242880, 1048576);
  cast_f32_bf16<<<4096, blk, 0, stream>>>(wo, wob, 4194304);

  // fused QKV projection (bf16 out)
  gemm_nt_bf16<1><<<dim3(24, 32), blk, 0, stream>>>(xb, wqkvb, qkv, BS_, QSTRIDE, HID_);

  // RoPE (Q gets 1/sqrt(d) folded in); K slice at col offset 2048
  rope_bf16<16, 4, QSTRIDE, 1><<<16384, blk, 0, stream>>>(qkv, cosb, sinb);
  rope_bf16<4, 2, QSTRIDE, 0><<<4096, blk, 0, stream>>>(qkv + 2048, cosb, sinb);

  // causal SDPA
  attn_fwd_bf16<<<dim3(32, 32), blk, 0, stream>>>(qkv, attnb);

  // output projection (fp32 out)
  gemm_nt_bf16<0><<<dim3(16, 32), blk, 0, stream>>>(attnb, wob, out, BS_, HID_, HID_);
}

// Round 4
// 379.080 us; speedup vs baseline: 8.3989x; 1.1907x over previous
//
#include <hip/hip_runtime.h>
#include <hip/hip_bf16.h>
#include <math.h>

#define B_    2
#define S_    2048
#define HID_  2048
#define H_    16
#define HKV_  4
#define HD_   128
#define BS_   (B_*S_)
#define QSTRIDE 3072          // fused qkv row: [q 2048 | k 512 | v 512]
#define L2E 1.4426950408889634f

typedef __attribute__((ext_vector_type(8))) short bf16x8;
typedef __attribute__((ext_vector_type(4))) float f32x4;
typedef __attribute__((ext_vector_type(16))) float f32x16;
typedef unsigned int uint;

typedef __attribute__((address_space(3))) void lds_void;
typedef __attribute__((address_space(1))) const void gbl_cvoid;

__device__ __forceinline__ void load_lds16(const void* g, void* l) {
  __builtin_amdgcn_global_load_lds((gbl_cvoid*)g, (lds_void*)l, 16, 0, 0);
}

__device__ __forceinline__ unsigned short f2bf(float f) {
  uint u = __float_as_uint(f);
  u = (u + 0x7fff + ((u >> 16) & 1)) >> 16;   // RNE
  return (unsigned short)u;
}
__device__ __forceinline__ float bf2f(unsigned short u) {
  return __uint_as_float(((uint)u) << 16);
}
__device__ __forceinline__ uint cvtpk_bf16(float lo, float hi) {
  uint r;
  asm("v_cvt_pk_bf16_f32 %0, %1, %2" : "=v"(r) : "v"(lo), "v"(hi));
  return r;
}
// v_permlane32_swap_b32 a, b: a<[0:31] keeps, a[32:63] <- b[0:31];
// b[0:31] <- a[32:63], b[32:63] keeps.  (i.e. a = {A_lo, B_lo}, b = {A_hi, B_hi})
__device__ __forceinline__ void swap32(uint& a, uint& b) {
  asm("v_permlane32_swap_b32 %0, %1" : "+v"(a), "+v"(b));
}

// ---------------------------------------------------------------------------
// fp32 -> bf16 cast
// ---------------------------------------------------------------------------
__global__ __launch_bounds__(256) void cast_f32_bf16(
    const float* __restrict__ src, unsigned short* __restrict__ dst, int n)
{
  int i = (blockIdx.x * 256 + threadIdx.x) * 4;
  if (i < n) {
    float4 v = *(const float4*)(src + i);
    ushort4 o;
    o.x = f2bf(v.x); o.y = f2bf(v.y); o.z = f2bf(v.z); o.w = f2bf(v.w);
    *(ushort4*)(dst + i) = o;
  }
}

// ---------------------------------------------------------------------------
// bf16 NT-GEMM (m97 structure): C[M][N] = A[M][K] @ W[N][K]^T, fp32 accum.
// ---------------------------------------------------------------------------
template <int WRITE_BF16>
__global__ __launch_bounds__(256) void gemm_nt_bf16(
    const unsigned short* __restrict__ A, const unsigned short* __restrict__ W,
    void* __restrict__ Cv, int M, int N, int K)
{
  __shared__ unsigned short As[128 * 32];
  __shared__ unsigned short Bs[128 * 32];

  const int tid = threadIdx.x;
  const int bm = blockIdx.y * 128, bn = blockIdx.x * 128;
  const int w = tid >> 6, lane = tid & 63;
  const int c_ = lane & 15, g4 = lane >> 4;
  const int wr = (w >> 1) * 64, wc = (w & 1) * 64;

  f32x4 acc[4][4];
#pragma unroll
  for (int i = 0; i < 4; ++i)
#pragma unroll
    for (int j = 0; j < 4; ++j) acc[i][j] = (f32x4){0.f, 0.f, 0.f, 0.f};

  for (int k0 = 0; k0 < K; k0 += 32) {
#pragma unroll
    for (int i = 0; i < 2; ++i) {
      int db = i * 4096 + tid * 16;
      int row = db >> 6;
      int cb = (db & 63) ^ ((row & 3) << 4);
      load_lds16((const char*)(A + (size_t)(bm + row) * K + k0) + cb, (char*)As + db);
      load_lds16((const char*)(W + (size_t)(bn + row) * K + k0) + cb, (char*)Bs + db);
    }
    __syncthreads();

    bf16x8 af[4], bfr[4];
#pragma unroll
    for (int i = 0; i < 4; ++i) {
      int ra = wr + i * 16 + c_;
      af[i] = *(const bf16x8*)((const char*)As + ra * 64 + ((g4 * 16) ^ ((ra & 3) << 4)));
      int rb = wc + i * 16 + c_;
      bfr[i] = *(const bf16x8*)((const char*)Bs + rb * 64 + ((g4 * 16) ^ ((rb & 3) << 4)));
    }
#pragma unroll
    for (int mi = 0; mi < 4; ++mi)
#pragma unroll
      for (int ni = 0; ni < 4; ++ni)
        acc[mi][ni] = __builtin_amdgcn_mfma_f32_16x16x32_bf16(af[mi], bfr[ni], acc[mi][ni], 0, 0, 0);
    __syncthreads();
  }

#pragma unroll
  for (int mi = 0; mi < 4; ++mi) {
#pragma unroll
    for (int r = 0; r < 4; ++r) {
      size_t row = bm + wr + mi * 16 + g4 * 4 + r;
#pragma unroll
      for (int ni = 0; ni < 4; ++ni) {
        size_t col = bn + wc + ni * 16 + c_;
        float v = acc[mi][ni][r];
        if (WRITE_BF16)
          ((unsigned short*)Cv)[row * N + col] = f2bf(v);
        else
          ((float*)Cv)[row * N + col] = v;
      }
    }
  }
}

// ---------------------------------------------------------------------------
// RoPE in place on bf16.
// ---------------------------------------------------------------------------
template <int NH, int LOGNH, int ROWE, int SCALE>
__global__ __launch_bounds__(256) void rope_bf16(
    unsigned short* __restrict__ p, const float* __restrict__ cosb,
    const float* __restrict__ sinb)
{
  int idx = blockIdx.x * 256 + threadIdx.x;
  int d = idx & 63;
  int h = (idx >> 6) & (NH - 1);
  int s = (idx >> (6 + LOGNH)) & (S_ - 1);
  int b = idx >> (6 + LOGNH + 11);

  size_t off = ((size_t)b * S_ + s) * ROWE + h * HD_ + d;
  float x1 = bf2f(p[off]);
  float x2 = bf2f(p[off + 64]);
  float c1 = cosb[s * HD_ + d],      s1 = sinb[s * HD_ + d];
  float c2 = cosb[s * HD_ + d + 64], s2 = sinb[s * HD_ + d + 64];
  float o1 = x1 * c1 - x2 * s1;
  float o2 = x2 * c2 + x1 * s2;
  if (SCALE) { o1 *= 0.08838834764831845f; o2 *= 0.08838834764831845f; }
  p[off]      = f2bf(o1);
  p[off + 64] = f2bf(o2);
}

// ---------------------------------------------------------------------------
// Causal flash attention, swapped-operand 32x32x16 MFMA (m214 structure).
// 4 waves x 32 q-rows (QBLK=128), KVBLK=64 (2x 32-k subtiles).
// S^T = mfma(K, Q): lane owns q-col = lane&31; k-rows in regs -> in-register
// softmax (no LDS P). P->bf16 via v_cvt_pk_bf16_f32 + v_permlane32_swap.
// O^T accumulated via mfma(V^T, P). K in LDS (glds, XOR-swz); V^T reg-
// transposed into LDS with rotated-write-order XOR-swz. Double-buffered,
// one barrier/tile. Defer-max (THR=8). Paired-qt grid for load balance.
// ---------------------------------------------------------------------------
__global__ __launch_bounds__(256) void attn_fwd_bf16(
    const unsigned short* __restrict__ QKV, unsigned short* __restrict__ O)
{
  __shared__ __align__(16) char lds[65536];   // K: 2x16KB @0, V^T: 2x16KB @32768

  const int tid = threadIdx.x;
  const int lane = tid & 63;
  const int wq = tid >> 6;
  const int ql = lane & 31;
  const int hi = lane >> 5;

  // paired-qt grid: blocks bid and bid+256 get qt summing to 15
  const int bid = blockIdx.x;
  const int halfg = bid >> 8, rem = bid & 255;
  const int bh = rem >> 3, a2 = rem & 7;
  const int qt = halfg ? (15 - 2 * a2) : (2 * a2);
  const int b = bh >> 4, h = bh & 15, kh = h >> 2;
  const int q0 = qt * 128;
  const int qglob = q0 + wq * 32 + ql;
  const int ktmax_w = (q0 + wq * 32 + 31) >> 6;   // last tile this wave needs
  const int ntiles = 2 * qt + 2;

  // Q B-frags: lane holds Q[q=qglob][d = ds*16 + hi*8 + j]
  bf16x8 qf[8];
  {
    const unsigned short* qsrc =
        QKV + ((size_t)(b * S_) + qglob) * QSTRIDE + h * HD_ + hi * 8;
#pragma unroll
    for (int ds = 0; ds < 8; ++ds) qf[ds] = *(const bf16x8*)(qsrc + ds * 16);
  }

  f32x16 acc[4];
#pragma unroll
  for (int dt = 0; dt < 4; ++dt)
#pragma unroll
    for (int r = 0; r < 16; ++r) acc[dt][r] = 0.f;
  float m_ = -3.0e38f, l_ = 0.f;

  const char* Kg = (const char*)(QKV + (size_t)b * S_ * QSTRIDE + 2048 + kh * HD_);
  const unsigned short* Vg = QKV + (size_t)b * S_ * QSTRIDE + 2560 + kh * HD_;

  // V^T staging mapping: thread owns k0..k0+3 x d-chunk dc*8..dc*8+7
  const int dc = tid & 15;
  const int kq4 = (tid >> 4) * 4;
  bf16x8 vr[4];

  // ---- prologue: stage tile 0 ----
#pragma unroll
  for (int p = 0; p < 4; ++p) {
    int db = p * 4096 + tid * 16;
    int row = db >> 8;
    int cb = (db & 255) ^ ((row & 7) << 4);
    load_lds16(Kg + (size_t)row * (QSTRIDE * 2) + cb, lds + db);
  }
  {
    const unsigned short* vs = Vg + (size_t)kq4 * QSTRIDE + dc * 8;
#pragma unroll
    for (int i = 0; i < 4; ++i) vr[i] = *(const bf16x8*)(vs + i * QSTRIDE);
#pragma unroll
    for (int s = 0; s < 8; ++s) {
      int j = (dc + s) & 7;
      int d = dc * 8 + j;
      uint w0 = (uint)(unsigned short)vr[0][j] | ((uint)(unsigned short)vr[1][j] << 16);
      uint w1 = (uint)(unsigned short)vr[2][j] | ((uint)(unsigned short)vr[3][j] << 16);
      *(uint2*)(lds + 32768 + d * 128 + ((kq4 * 2) ^ (j << 4))) = make_uint2(w0, w1);
    }
  }
  __syncthreads();

  for (int kt = 0; kt < ntiles; ++kt) {
    const int cur = kt & 1;
    const bool pf = (kt + 1 < ntiles);

    // ---- prefetch tile kt+1: K -> LDS (async), V -> regs ----
    if (pf) {
#pragma unroll
      for (int p = 0; p < 4; ++p) {
        int db = p * 4096 + tid * 16;
        int row = db >> 8;
        int cb = (db & 255) ^ ((row & 7) << 4);
        load_lds16(Kg + (size_t)((kt + 1) * 64 + row) * (QSTRIDE * 2) + cb,
                   lds + (cur ^ 1) * 16384 + db);
      }
      const unsigned short* vs = Vg + (size_t)((kt + 1) * 64 + kq4) * QSTRIDE + dc * 8;
#pragma unroll
      for (int i = 0; i < 4; ++i) vr[i] = *(const bf16x8*)(vs + i * QSTRIDE);
    }

    // ---- compute (skip fully-masked tiles for this wave) ----
    if (kt <= ktmax_w) {
      const char* ksc = lds + cur * 16384;
      const char* vtc = lds + 32768 + cur * 16384;
#pragma unroll
      for (int ks2 = 0; ks2 < 2; ++ks2) {
        // S^T[32k][32q] = mfma(K-frag, Q-frag) over 8 d-steps
        f32x16 s;
#pragma unroll
        for (int r = 0; r < 16; ++r) s[r] = 0.f;
        const int kk = ks2 * 32 + ql;
        const char* krow = ksc + kk * 256;
        const int ksw = (kk & 7) << 4;
#pragma unroll
        for (int ds = 0; ds < 8; ++ds) {
          bf16x8 kf = *(const bf16x8*)(krow + ((ds * 32 + hi * 16) ^ ksw));
          s = __builtin_amdgcn_mfma_f32_32x32x16_bf16(kf, qf[ds], s, 0, 0, 0);
        }

        // causal mask (only on the wave's diagonal tile)
        if (kt == ktmax_w) {
          const int kb = kt * 64 + ks2 * 32 + 4 * hi;
#pragma unroll
          for (int r = 0; r < 16; ++r) {
            int kg = kb + (r & 3) + 8 * (r >> 2);
            if (kg > qglob) s[r] = -3.0e38f;
          }
        }

        // in-register online softmax (lane owns one q-row of S^T)
        float mx = s[0];
#pragma unroll
        for (int r = 1; r < 16; ++r) mx = fmaxf(mx, s[r]);
        mx = fmaxf(mx, __shfl_xor(mx, 32));
        const bool nd = mx > m_ + 8.f;
        float fr = 1.f;
        if (__any(nd)) {
          float mn = nd ? mx : m_;
          fr = nd ? exp2f((m_ - mn) * L2E) : 1.f;
          m_ = mn;
#pragma unroll
          for (int dt = 0; dt < 4; ++dt)
#pragma unroll
            for (int r = 0; r < 16; ++r) acc[dt][r] *= fr;
        }
        float pr[16];
        float sum = 0.f;
#pragma unroll
        for (int r = 0; r < 16; ++r) {
          pr[r] = exp2f((s[r] - m_) * L2E);
          sum += pr[r];
        }
        sum += __shfl_xor(sum, 32);
        l_ = l_ * fr + sum;

        // P -> bf16 B-frags via cvt_pk + permlane32_swap (T12)
        uint wA0 = cvtpk_bf16(pr[0], pr[1]);
        uint wA1 = cvtpk_bf16(pr[2], pr[3]);
        uint wB0 = cvtpk_bf16(pr[4], pr[5]);
        uint wB1 = cvtpk_bf16(pr[6], pr[7]);
        swap32(wA0, wB0);
        swap32(wA1, wB1);
        uint wC0 = cvtpk_bf16(pr[8], pr[9]);
        uint wC1 = cvtpk_bf16(pr[10], pr[11]);
        uint wD0 = cvtpk_bf16(pr[12], pr[13]);
        uint wD1 = cvtpk_bf16(pr[14], pr[15]);
        swap32(wC0, wD0);
        swap32(wC1, wD1);
        union { uint u[4]; bf16x8 v; } p0, p1;
        p0.u[0] = wA0; p0.u[1] = wA1; p0.u[2] = wB0; p0.u[3] = wB1;
        p1.u[0] = wC0; p1.u[1] = wC1; p1.u[2] = wD0; p1.u[3] = wD1;

        // PV: O^T[d][q] += V^T-frag x P-frag
#pragma unroll
        for (int dt = 0; dt < 4; ++dt) {
          const int dr = dt * 32 + ql;
          const char* vrow = vtc + dr * 128;
          const int vsw = (dr & 7) << 4;
          bf16x8 v0 = *(const bf16x8*)(vrow + ((ks2 * 64 + hi * 16) ^ vsw));
          acc[dt] = __builtin_amdgcn_mfma_f32_32x32x16_bf16(v0, p0.v, acc[dt], 0, 0, 0);
          bf16x8 v1 = *(const bf16x8*)(vrow + ((ks2 * 64 + 32 + hi * 16) ^ vsw));
          acc[dt] = __builtin_amdgcn_mfma_f32_32x32x16_bf16(v1, p1.v, acc[dt], 0, 0, 0);
        }
      }
    }

    // ---- late V^T write into next buffer ----
    if (pf) {
#pragma unroll
      for (int s = 0; s < 8; ++s) {
        int j = (dc + s) & 7;
        int d = dc * 8 + j;
        uint w0 = (uint)(unsigned short)vr[0][j] | ((uint)(unsigned short)vr[1][j] << 16);
        uint w1 = (uint)(unsigned short)vr[2][j] | ((uint)(unsigned short)vr[3][j] << 16);
        *(uint2*)(lds + 32768 + (cur ^ 1) * 16384 + d * 128 + ((kq4 * 2) ^ (j << 4))) =
            make_uint2(w0, w1);
      }
    }
    __syncthreads();
  }

  // ---- epilogue: normalize, transpose O^T -> O via per-wave LDS scratch ----
  {
    const float inv = 1.f / l_;
    char* wsc = lds + wq * 8704;     // 32 rows x 272B
#pragma unroll
    for (int dt = 0; dt < 4; ++dt) {
#pragma unroll
      for (int i = 0; i < 8; ++i) {
        uint wv = cvtpk_bf16(acc[dt][2 * i] * inv, acc[dt][2 * i + 1] * inv);
        int d = 2 * (i & 1) + 8 * (i >> 1) + 4 * hi + 32 * dt;
        *(uint*)(wsc + ql * 272 + d * 2) = wv;
      }
    }
    // wave-local: reads see own wave's writes after lgkmcnt (no barrier needed)
#pragma unroll
    for (int j = 0; j < 8; ++j) {
      bf16x8 ov = *(const bf16x8*)(wsc + ql * 272 + hi * 128 + j * 16);
      unsigned short* ob = O + ((size_t)(b * S_) + q0 + wq * 32 + ql) * (H_ * HD_) +
                           h * HD_ + hi * 64 + j * 8;
      *(bf16x8*)ob = ov;
    }
  }
}

// ---------------------------------------------------------------------------
extern "C" void kernel_launch(void* const* d_in, const int* in_sizes, int n_in,
                              void* d_out, int out_size, void* d_ws, size_t ws_size,
                              hipStream_t stream) {
  const float* x    = (const float*)d_in[0];
  const float* cosb = (const float*)d_in[1];
  const float* sinb = (const float*)d_in[2];
  const float* wq   = (const float*)d_in[3];
  const float* wk   = (const float*)d_in[4];
  const float* wv   = (const float*)d_in[5];
  const float* wo   = (const float*)d_in[6];
  float* out        = (float*)d_out;

  unsigned short* xb     = (unsigned short*)d_ws;
  unsigned short* wqkvb  = xb + 8388608;         // x:    4096x2048
  unsigned short* wob    = wqkvb + 6291456;      // wqkv: 3072x2048
  unsigned short* qkv    = wob + 4194304;        // wo:   2048x2048
  unsigned short* attnb  = qkv + 12582912;       // qkv:  4096x3072

  dim3 blk(256);

  cast_f32_bf16<<<8192, blk, 0, stream>>>(x, xb, 8388608);
  cast_f32_bf16<<<4096, blk, 0, stream>>>(wq, wqkvb, 4194304);
  cast_f32_bf16<<<1024, blk, 0, stream>>>(wk, wqkvb + 4194304, 1048576);
  cast_f32_bf16<<<1024, blk, 0, stream>>>(wv, wqkvb + 5242880, 1048576);
  cast_f32_bf16<<<4096, blk, 0, stream>>>(wo, wob, 4194304);

  gemm_nt_bf16<1><<<dim3(24, 32), blk, 0, stream>>>(xb, wqkvb, qkv, BS_, QSTRIDE, HID_);

  rope_bf16<16, 4, QSTRIDE, 1><<<16384, blk, 0, stream>>>(qkv, cosb, sinb);
  rope_bf16<4, 2, QSTRIDE, 0><<<4096, blk, 0, stream>>>(qkv + 2048, cosb, sinb);

  attn_fwd_bf16<<<512, blk, 0, stream>>>(qkv, attnb);

  gemm_nt_bf16<0><<<dim3(16, 32), blk, 0, stream>>>(attnb, wob, out, BS_, HID_, HID_);
}

// Round 5
// 345.364 us; speedup vs baseline: 9.2188x; 1.0976x over previous
//
#include <hip/hip_runtime.h>
#include <hip/hip_bf16.h>
#include <math.h>

#define B_    2
#define S_    2048
#define HID_  2048
#define H_    16
#define HKV_  4
#define HD_   128
#define BS_   (B_*S_)
#define QSTRIDE 3072          // fused qkv row: [q 2048 | k 512 | v 512]
#define L2E 1.4426950408889634f

typedef __attribute__((ext_vector_type(8))) short bf16x8;
typedef __attribute__((ext_vector_type(4))) float f32x4;
typedef __attribute__((ext_vector_type(16))) float f32x16;
typedef unsigned int uint;

typedef __attribute__((address_space(3))) void lds_void;
typedef __attribute__((address_space(1))) const void gbl_cvoid;

__device__ __forceinline__ void load_lds16(const void* g, void* l) {
  __builtin_amdgcn_global_load_lds((gbl_cvoid*)g, (lds_void*)l, 16, 0, 0);
}

__device__ __forceinline__ unsigned short f2bf(float f) {
  uint u = __float_as_uint(f);
  u = (u + 0x7fff + ((u >> 16) & 1)) >> 16;   // RNE
  return (unsigned short)u;
}
__device__ __forceinline__ float bf2f(unsigned short u) {
  return __uint_as_float(((uint)u) << 16);
}
__device__ __forceinline__ uint cvtpk_bf16(float lo, float hi) {
  uint r;
  asm("v_cvt_pk_bf16_f32 %0, %1, %2" : "=v"(r) : "v"(lo), "v"(hi));
  return r;
}
__device__ __forceinline__ void swap32(uint& a, uint& b) {
  asm("v_permlane32_swap_b32 %0, %1" : "+v"(a), "+v"(b));
}

// ---------------------------------------------------------------------------
// fp32 -> bf16 cast
// ---------------------------------------------------------------------------
__global__ __launch_bounds__(256) void cast_f32_bf16(
    const float* __restrict__ src, unsigned short* __restrict__ dst, int n)
{
  int i = (blockIdx.x * 256 + threadIdx.x) * 4;
  if (i < n) {
    float4 v = *(const float4*)(src + i);
    ushort4 o;
    o.x = f2bf(v.x); o.y = f2bf(v.y); o.z = f2bf(v.z); o.w = f2bf(v.w);
    *(ushort4*)(dst + i) = o;
  }
}

// ---------------------------------------------------------------------------
// bf16 NT-GEMM, 256-row tile, BK=64, 512 threads (8 waves, 2M x 4N),
// 4-phase K-loop with counted vmcnt (T3+T4) + setprio (T5).
// C[M][N] = A[M][K] @ W[N][K]^T, fp32 accum, MFMA 16x16x32.
//
// LDS per parity buffer: A = 2 slabs (klo/khi) of 256 rows x 64 B;
// B = 2 slabs of BN rows x 64 B. Slot-XOR involution (slot ^= row&3) applied
// on BOTH the staging global source and the ds_read address (rule #21).
//
// Per tile t (4 phases): stage tile t+1 2 rounds/phase; sync points:
//   loop-top:  vmcnt(KHI) + barrier  -> t's klo landed (khi may fly)
//   mid-tile:  vmcnt(KLO) + barrier  -> t's khi landed (t+1 klo may fly)
// Loads issued ~3 phases (~1800 cyc) before their wait -> HBM latency hidden.
// ---------------------------------------------------------------------------
template <int BN, int WRITE_BF16>
__global__ __launch_bounds__(512, 2) void gemm_nt_8ph(
    const unsigned short* __restrict__ A, const unsigned short* __restrict__ W,
    void* __restrict__ Cv, int M, int N, int K)
{
  constexpr int ASLAB = 16384;            // 256 rows x 64 B
  constexpr int BSLAB = BN * 64;
  constexpr int ABUF  = 2 * ASLAB;
  constexpr int BBUF  = 2 * BSLAB;
  constexpr int RN    = BN / 4;           // per-wave N
  constexpr int NTN   = RN / 16;          // n-tiles per wave (4 or 2)

  __shared__ __align__(16) char lds_[2 * ABUF + 2 * BBUF];
  char* const AL = lds_;
  char* const BL = lds_ + 2 * ABUF;

  const int tid = threadIdx.x;
  const int lane = tid & 63;
  const int wid = tid >> 6;
  const int wm = wid >> 2, wn = wid & 3;
  const int c_ = lane & 15, g4 = lane >> 4;
  const int bm = blockIdx.y * 256, bn = blockIdx.x * BN;

  const size_t rs = (size_t)K * 2;
  const char* Ag = (const char*)A + (size_t)bm * rs;
  const char* Bg = (const char*)W + (size_t)bn * rs;

  const int stq = tid >> 2;                         // staging row in round
  const int stslot = ((tid & 3) ^ (stq & 3)) * 16;  // pre-swizzled src slot
  const int fsl = (g4 ^ (c_ & 3)) << 4;             // frag read slot (lane-const)
  const int dst = tid * 16;

  f32x4 acc[2][4][NTN];
#pragma unroll
  for (int mh = 0; mh < 2; ++mh)
#pragma unroll
    for (int mt = 0; mt < 4; ++mt)
#pragma unroll
      for (int nt = 0; nt < NTN; ++nt) acc[mh][mt][nt] = (f32x4){0.f, 0.f, 0.f, 0.f};

  const int NT = K / 64;

  auto stA = [&](char* buf, int slab, int half, int kbyte) {
    load_lds16(Ag + (size_t)(half * 128 + stq) * rs + kbyte + stslot,
               buf + slab * ASLAB + half * 8192 + dst);
  };
  auto stB = [&](char* buf, int slab, int half, int kbyte) {
    load_lds16(Bg + (size_t)(half * 128 + stq) * rs + kbyte + stslot,
               buf + slab * BSLAB + half * 8192 + dst);
  };

  // ---- prologue: stage tile 0 into buffer 0 (klo group first, then khi) ----
  stA(AL, 0, 0, 0); stB(BL, 0, 0, 0); stA(AL, 0, 1, 0);
  if constexpr (BN == 256) stB(BL, 0, 1, 0);
  stA(AL, 1, 0, 64); stB(BL, 1, 0, 64); stA(AL, 1, 1, 64);
  if constexpr (BN == 256) stB(BL, 1, 1, 64);

  const int afb = (wm * 128 + c_) * 64 + fsl;
  const int bfb = (wn * RN + c_) * 64 + fsl;

#define WAITK do { if constexpr (BN == 256) asm volatile("s_waitcnt vmcnt(4)" ::: "memory"); \
                   else                     asm volatile("s_waitcnt vmcnt(3)" ::: "memory"); \
                   __builtin_amdgcn_s_barrier(); \
                   __builtin_amdgcn_sched_barrier(0); } while (0)

  for (int t = 0; t < NT; ++t) {
    const char* Ac = AL + (t & 1) * ABUF;
    const char* Bc = BL + (t & 1) * BBUF;
    char* An = AL + ((t + 1) & 1) * ABUF;
    char* Bn = BL + ((t + 1) & 1) * BBUF;
    const int tn = (t + 1 < NT) ? t + 1 : 0;   // wrapped prefetch (harmless)
    const int kb = tn * 128;

    WAITK;   // t's klo landed (all waves)

    bf16x8 af[4], bf0[NTN];

    // ---- phase 1: ks=0, mh=0 ----
#pragma unroll
    for (int mt = 0; mt < 4; ++mt)
      af[mt] = *(const bf16x8*)(Ac + afb + mt * 1024);
#pragma unroll
    for (int nt = 0; nt < NTN; ++nt)
      bf0[nt] = *(const bf16x8*)(Bc + bfb + nt * 1024);
    stA(An, 0, 0, kb); stB(Bn, 0, 0, kb);
    __builtin_amdgcn_s_setprio(1);
#pragma unroll
    for (int mt = 0; mt < 4; ++mt)
#pragma unroll
      for (int nt = 0; nt < NTN; ++nt)
        acc[0][mt][nt] = __builtin_amdgcn_mfma_f32_16x16x32_bf16(af[mt], bf0[nt], acc[0][mt][nt], 0, 0, 0);
    __builtin_amdgcn_s_setprio(0);

    // ---- phase 2: ks=0, mh=1 (reuse bf0) ----
#pragma unroll
    for (int mt = 0; mt < 4; ++mt)
      af[mt] = *(const bf16x8*)(Ac + afb + 4096 + mt * 1024);
    stA(An, 0, 1, kb);
    if constexpr (BN == 256) stB(Bn, 0, 1, kb);
    __builtin_amdgcn_s_setprio(1);
#pragma unroll
    for (int mt = 0; mt < 4; ++mt)
#pragma unroll
      for (int nt = 0; nt < NTN; ++nt)
        acc[1][mt][nt] = __builtin_amdgcn_mfma_f32_16x16x32_bf16(af[mt], bf0[nt], acc[1][mt][nt], 0, 0, 0);
    __builtin_amdgcn_s_setprio(0);

    WAITK;   // t's khi landed (all waves)

    // ---- phase 3: ks=1, mh=0 ----
#pragma unroll
    for (int mt = 0; mt < 4; ++mt)
      af[mt] = *(const bf16x8*)(Ac + ASLAB + afb + mt * 1024);
#pragma unroll
    for (int nt = 0; nt < NTN; ++nt)
      bf0[nt] = *(const bf16x8*)(Bc + BSLAB + bfb + nt * 1024);
    stA(An, 1, 0, kb + 64); stB(Bn, 1, 0, kb + 64);
    __builtin_amdgcn_s_setprio(1);
#pragma unroll
    for (int mt = 0; mt < 4; ++mt)
#pragma unroll
      for (int nt = 0; nt < NTN; ++nt)
        acc[0][mt][nt] = __builtin_amdgcn_mfma_f32_16x16x32_bf16(af[mt], bf0[nt], acc[0][mt][nt], 0, 0, 0);
    __builtin_amdgcn_s_setprio(0);

    // ---- phase 4: ks=1, mh=1 ----
#pragma unroll
    for (int mt = 0; mt < 4; ++mt)
      af[mt] = *(const bf16x8*)(Ac + ASLAB + afb + 4096 + mt * 1024);
    stA(An, 1, 1, kb + 64);
    if constexpr (BN == 256) stB(Bn, 1, 1, kb + 64);
    __builtin_amdgcn_s_setprio(1);
#pragma unroll
    for (int mt = 0; mt < 4; ++mt)
#pragma unroll
      for (int nt = 0; nt < NTN; ++nt)
        acc[1][mt][nt] = __builtin_amdgcn_mfma_f32_16x16x32_bf16(af[mt], bf0[nt], acc[1][mt][nt], 0, 0, 0);
    __builtin_amdgcn_s_setprio(0);
  }
#undef WAITK

  // ---- epilogue: C row = g4*4 + reg, col = c_ (verified layout) ----
#pragma unroll
  for (int mh = 0; mh < 2; ++mh)
#pragma unroll
    for (int mt = 0; mt < 4; ++mt)
#pragma unroll
      for (int r = 0; r < 4; ++r) {
        size_t row = bm + wm * 128 + mh * 64 + mt * 16 + g4 * 4 + r;
#pragma unroll
        for (int nt = 0; nt < NTN; ++nt) {
          size_t col = bn + wn * RN + nt * 16 + c_;
          float v = acc[mh][mt][nt][r];
          if (WRITE_BF16)
            ((unsigned short*)Cv)[row * N + col] = f2bf(v);
          else
            ((float*)Cv)[row * N + col] = v;
        }
      }
}

// ---------------------------------------------------------------------------
// RoPE in place on bf16.
// ---------------------------------------------------------------------------
template <int NH, int LOGNH, int ROWE, int SCALE>
__global__ __launch_bounds__(256) void rope_bf16(
    unsigned short* __restrict__ p, const float* __restrict__ cosb,
    const float* __restrict__ sinb)
{
  int idx = blockIdx.x * 256 + threadIdx.x;
  int d = idx & 63;
  int h = (idx >> 6) & (NH - 1);
  int s = (idx >> (6 + LOGNH)) & (S_ - 1);
  int b = idx >> (6 + LOGNH + 11);

  size_t off = ((size_t)b * S_ + s) * ROWE + h * HD_ + d;
  float x1 = bf2f(p[off]);
  float x2 = bf2f(p[off + 64]);
  float c1 = cosb[s * HD_ + d],      s1 = sinb[s * HD_ + d];
  float c2 = cosb[s * HD_ + d + 64], s2 = sinb[s * HD_ + d + 64];
  float o1 = x1 * c1 - x2 * s1;
  float o2 = x2 * c2 + x1 * s2;
  if (SCALE) { o1 *= 0.08838834764831845f; o2 *= 0.08838834764831845f; }
  p[off]      = f2bf(o1);
  p[off + 64] = f2bf(o2);
}

// ---------------------------------------------------------------------------
// Causal flash attention, swapped-operand 32x32x16 MFMA (unchanged from R4).
// ---------------------------------------------------------------------------
__global__ __launch_bounds__(256) void attn_fwd_bf16(
    const unsigned short* __restrict__ QKV, unsigned short* __restrict__ O)
{
  __shared__ __align__(16) char lds[65536];   // K: 2x16KB @0, V^T: 2x16KB @32768

  const int tid = threadIdx.x;
  const int lane = tid & 63;
  const int wq = tid >> 6;
  const int ql = lane & 31;
  const int hi = lane >> 5;

  const int bid = blockIdx.x;
  const int halfg = bid >> 8, rem = bid & 255;
  const int bh = rem >> 3, a2 = rem & 7;
  const int qt = halfg ? (15 - 2 * a2) : (2 * a2);
  const int b = bh >> 4, h = bh & 15, kh = h >> 2;
  const int q0 = qt * 128;
  const int qglob = q0 + wq * 32 + ql;
  const int ktmax_w = (q0 + wq * 32 + 31) >> 6;
  const int ntiles = 2 * qt + 2;

  bf16x8 qf[8];
  {
    const unsigned short* qsrc =
        QKV + ((size_t)(b * S_) + qglob) * QSTRIDE + h * HD_ + hi * 8;
#pragma unroll
    for (int ds = 0; ds < 8; ++ds) qf[ds] = *(const bf16x8*)(qsrc + ds * 16);
  }

  f32x16 acc[4];
#pragma unroll
  for (int dt = 0; dt < 4; ++dt)
#pragma unroll
    for (int r = 0; r < 16; ++r) acc[dt][r] = 0.f;
  float m_ = -3.0e38f, l_ = 0.f;

  const char* Kg = (const char*)(QKV + (size_t)b * S_ * QSTRIDE + 2048 + kh * HD_);
  const unsigned short* Vg = QKV + (size_t)b * S_ * QSTRIDE + 2560 + kh * HD_;

  const int dc = tid & 15;
  const int kq4 = (tid >> 4) * 4;
  bf16x8 vr[4];

#pragma unroll
  for (int p = 0; p < 4; ++p) {
    int db = p * 4096 + tid * 16;
    int row = db >> 8;
    int cb = (db & 255) ^ ((row & 7) << 4);
    load_lds16(Kg + (size_t)row * (QSTRIDE * 2) + cb, lds + db);
  }
  {
    const unsigned short* vs = Vg + (size_t)kq4 * QSTRIDE + dc * 8;
#pragma unroll
    for (int i = 0; i < 4; ++i) vr[i] = *(const bf16x8*)(vs + i * QSTRIDE);
#pragma unroll
    for (int s = 0; s < 8; ++s) {
      int j = (dc + s) & 7;
      int d = dc * 8 + j;
      uint w0 = (uint)(unsigned short)vr[0][j] | ((uint)(unsigned short)vr[1][j] << 16);
      uint w1 = (uint)(unsigned short)vr[2][j] | ((uint)(unsigned short)vr[3][j] << 16);
      *(uint2*)(lds + 32768 + d * 128 + ((kq4 * 2) ^ (j << 4))) = make_uint2(w0, w1);
    }
  }
  __syncthreads();

  for (int kt = 0; kt < ntiles; ++kt) {
    const int cur = kt & 1;
    const bool pf = (kt + 1 < ntiles);

    if (pf) {
#pragma unroll
      for (int p = 0; p < 4; ++p) {
        int db = p * 4096 + tid * 16;
        int row = db >> 8;
        int cb = (db & 255) ^ ((row & 7) << 4);
        load_lds16(Kg + (size_t)((kt + 1) * 64 + row) * (QSTRIDE * 2) + cb,
                   lds + (cur ^ 1) * 16384 + db);
      }
      const unsigned short* vs = Vg + (size_t)((kt + 1) * 64 + kq4) * QSTRIDE + dc * 8;
#pragma unroll
      for (int i = 0; i < 4; ++i) vr[i] = *(const bf16x8*)(vs + i * QSTRIDE);
    }

    if (kt <= ktmax_w) {
      const char* ksc = lds + cur * 16384;
      const char* vtc = lds + 32768 + cur * 16384;
#pragma unroll
      for (int ks2 = 0; ks2 < 2; ++ks2) {
        f32x16 s;
#pragma unroll
        for (int r = 0; r < 16; ++r) s[r] = 0.f;
        const int kk = ks2 * 32 + ql;
        const char* krow = ksc + kk * 256;
        const int ksw = (kk & 7) << 4;
#pragma unroll
        for (int ds = 0; ds < 8; ++ds) {
          bf16x8 kf = *(const bf16x8*)(krow + ((ds * 32 + hi * 16) ^ ksw));
          s = __builtin_amdgcn_mfma_f32_32x32x16_bf16(kf, qf[ds], s, 0, 0, 0);
        }

        if (kt == ktmax_w) {
          const int kb = kt * 64 + ks2 * 32 + 4 * hi;
#pragma unroll
          for (int r = 0; r < 16; ++r) {
            int kg = kb + (r & 3) + 8 * (r >> 2);
            if (kg > qglob) s[r] = -3.0e38f;
          }
        }

        float mx = s[0];
#pragma unroll
        for (int r = 1; r < 16; ++r) mx = fmaxf(mx, s[r]);
        mx = fmaxf(mx, __shfl_xor(mx, 32));
        const bool nd = mx > m_ + 8.f;
        float fr = 1.f;
        if (__any(nd)) {
          float mn = nd ? mx : m_;
          fr = nd ? exp2f((m_ - mn) * L2E) : 1.f;
          m_ = mn;
#pragma unroll
          for (int dt = 0; dt < 4; ++dt)
#pragma unroll
            for (int r = 0; r < 16; ++r) acc[dt][r] *= fr;
        }
        float pr[16];
        float sum = 0.f;
#pragma unroll
        for (int r = 0; r < 16; ++r) {
          pr[r] = exp2f((s[r] - m_) * L2E);
          sum += pr[r];
        }
        sum += __shfl_xor(sum, 32);
        l_ = l_ * fr + sum;

        uint wA0 = cvtpk_bf16(pr[0], pr[1]);
        uint wA1 = cvtpk_bf16(pr[2], pr[3]);
        uint wB0 = cvtpk_bf16(pr[4], pr[5]);
        uint wB1 = cvtpk_bf16(pr[6], pr[7]);
        swap32(wA0, wB0);
        swap32(wA1, wB1);
        uint wC0 = cvtpk_bf16(pr[8], pr[9]);
        uint wC1 = cvtpk_bf16(pr[10], pr[11]);
        uint wD0 = cvtpk_bf16(pr[12], pr[13]);
        uint wD1 = cvtpk_bf16(pr[14], pr[15]);
        swap32(wC0, wD0);
        swap32(wC1, wD1);
        union { uint u[4]; bf16x8 v; } p0, p1;
        p0.u[0] = wA0; p0.u[1] = wA1; p0.u[2] = wB0; p0.u[3] = wB1;
        p1.u[0] = wC0; p1.u[1] = wC1; p1.u[2] = wD0; p1.u[3] = wD1;

#pragma unroll
        for (int dt = 0; dt < 4; ++dt) {
          const int dr = dt * 32 + ql;
          const char* vrow = vtc + dr * 128;
          const int vsw = (dr & 7) << 4;
          bf16x8 v0 = *(const bf16x8*)(vrow + ((ks2 * 64 + hi * 16) ^ vsw));
          acc[dt] = __builtin_amdgcn_mfma_f32_32x32x16_bf16(v0, p0.v, acc[dt], 0, 0, 0);
          bf16x8 v1 = *(const bf16x8*)(vrow + ((ks2 * 64 + 32 + hi * 16) ^ vsw));
          acc[dt] = __builtin_amdgcn_mfma_f32_32x32x16_bf16(v1, p1.v, acc[dt], 0, 0, 0);
        }
      }
    }

    if (pf) {
#pragma unroll
      for (int s = 0; s < 8; ++s) {
        int j = (dc + s) & 7;
        int d = dc * 8 + j;
        uint w0 = (uint)(unsigned short)vr[0][j] | ((uint)(unsigned short)vr[1][j] << 16);
        uint w1 = (uint)(unsigned short)vr[2][j] | ((uint)(unsigned short)vr[3][j] << 16);
        *(uint2*)(lds + 32768 + (cur ^ 1) * 16384 + d * 128 + ((kq4 * 2) ^ (j << 4))) =
            make_uint2(w0, w1);
      }
    }
    __syncthreads();
  }

  {
    const float inv = 1.f / l_;
    char* wsc = lds + wq * 8704;
#pragma unroll
    for (int dt = 0; dt < 4; ++dt) {
#pragma unroll
      for (int i = 0; i < 8; ++i) {
        uint wv = cvtpk_bf16(acc[dt][2 * i] * inv, acc[dt][2 * i + 1] * inv);
        int d = 2 * (i & 1) + 8 * (i >> 1) + 4 * hi + 32 * dt;
        *(uint*)(wsc + ql * 272 + d * 2) = wv;
      }
    }
#pragma unroll
    for (int j = 0; j < 8; ++j) {
      bf16x8 ov = *(const bf16x8*)(wsc + ql * 272 + hi * 128 + j * 16);
      unsigned short* ob = O + ((size_t)(b * S_) + q0 + wq * 32 + ql) * (H_ * HD_) +
                           h * HD_ + hi * 64 + j * 8;
      *(bf16x8*)ob = ov;
    }
  }
}

// ---------------------------------------------------------------------------
extern "C" void kernel_launch(void* const* d_in, const int* in_sizes, int n_in,
                              void* d_out, int out_size, void* d_ws, size_t ws_size,
                              hipStream_t stream) {
  const float* x    = (const float*)d_in[0];
  const float* cosb = (const float*)d_in[1];
  const float* sinb = (const float*)d_in[2];
  const float* wq   = (const float*)d_in[3];
  const float* wk   = (const float*)d_in[4];
  const float* wv   = (const float*)d_in[5];
  const float* wo   = (const float*)d_in[6];
  float* out        = (float*)d_out;

  unsigned short* xb     = (unsigned short*)d_ws;
  unsigned short* wqkvb  = xb + 8388608;         // x:    4096x2048
  unsigned short* wob    = wqkvb + 6291456;      // wqkv: 3072x2048
  unsigned short* qkv    = wob + 4194304;        // wo:   2048x2048
  unsigned short* attnb  = qkv + 12582912;       // qkv:  4096x3072

  dim3 blk(256);

  cast_f32_bf16<<<8192, blk, 0, stream>>>(x, xb, 8388608);
  cast_f32_bf16<<<4096, blk, 0, stream>>>(wq, wqkvb, 4194304);
  cast_f32_bf16<<<1024, blk, 0, stream>>>(wk, wqkvb + 4194304, 1048576);
  cast_f32_bf16<<<1024, blk, 0, stream>>>(wv, wqkvb + 5242880, 1048576);
  cast_f32_bf16<<<4096, blk, 0, stream>>>(wo, wob, 4194304);

  // fused QKV projection: 256x256 tiles, 192 blocks
  gemm_nt_8ph<256, 1><<<dim3(12, 16), dim3(512), 0, stream>>>(
      xb, wqkvb, qkv, BS_, QSTRIDE, HID_);

  rope_bf16<16, 4, QSTRIDE, 1><<<16384, blk, 0, stream>>>(qkv, cosb, sinb);
  rope_bf16<4, 2, QSTRIDE, 0><<<4096, blk, 0, stream>>>(qkv + 2048, cosb, sinb);

  attn_fwd_bf16<<<512, blk, 0, stream>>>(qkv, attnb);

  // output projection: 256x128 tiles, 256 blocks (1/CU exactly)
  gemm_nt_8ph<128, 0><<<dim3(16, 16), dim3(512), 0, stream>>>(
      attnb, wob, out, BS_, HID_, HID_);
}